// Round 17
// baseline (84.884 us; speedup 1.0000x reference)
//
#include <hip/hip_runtime.h>

#define NN 50000
#define NE 800000
#define DD 128

#define BK_SHIFT 6                 // 64 rows per bucket
#define BROWS 64
#define NBUCK 782                  // ceil(50000/64)
#define ECAP 2048                  // mean fill 1023, sigma ~32
#define CHUNK 8192
#define NCHUNK 98                  // ceil(800000/8192)
#define NGB 782                    // ceil(50000/64) gemm blocks

// ---------------- ws layout (float units) ----------------
#define OFF_H      0               // NN*DD bf16 = 3,200,000 floats
#define OFF_EBIN   3200000         // NBUCK*ECAP uint2 = 3,203,072 floats
#define OFF_CUR    6403072         // NBUCK ints
#define WS_FULL_FLOATS 6403854     // ~25.6 MB

typedef short short8 __attribute__((ext_vector_type(8)));
typedef float f32x4 __attribute__((ext_vector_type(4)));

static __device__ __forceinline__ unsigned int f2bf(float x) {
    unsigned int u = __float_as_uint(x);
    return (u + 0x7fffu + ((u >> 16) & 1u)) >> 16;  // RNE
}

// ============ K1: edge scatter (blocks 0..97, first) || MFMA GEMM (rest) ====
__global__ __launch_bounds__(256) void k1_scatter_gemm(
        const float* __restrict__ seq, const float* __restrict__ W,
        unsigned short* __restrict__ h,
        const int* __restrict__ erow, const int* __restrict__ ecol,
        const float* __restrict__ eval,
        int* __restrict__ gcur, uint2* __restrict__ ebin) {
    __shared__ uint4 lds4[3072];           // 48 KB
    char* lds = (char*)lds4;
    const int t = threadIdx.x;

    if (blockIdx.x < NCHUNK) {
        // ---- scatter: LDS hist -> global bump-reserve -> contiguous runs ----
        int* lh = (int*)lds4;              // [NBUCK] count, then cursor
        for (int i = t; i < NBUCK; i += 256) lh[i] = 0;
        __syncthreads();
        const int e0 = blockIdx.x * CHUNK;
        for (int i = t; i < CHUNK; i += 256) {
            int e = e0 + i;
            if (e < NE) atomicAdd(&lh[erow[e] >> BK_SHIFT], 1);
        }
        __syncthreads();
        for (int i = t; i < NBUCK; i += 256) {
            int c = lh[i];
            lh[i] = c ? atomicAdd(&gcur[i], c) : 0;   // count -> bucket-local base
        }
        __syncthreads();
        for (int i = t; i < CHUNK; i += 256) {
            int e = e0 + i;
            if (e < NE) {
                int r = erow[e], c = ecol[e];
                unsigned int vb = __float_as_uint(eval[e]);
                int k = r >> BK_SHIFT;
                int pos = atomicAdd(&lh[k], 1);
                if (pos < ECAP)
                    ebin[(size_t)k * ECAP + pos] =
                        make_uint2(((unsigned)r << 16) | (unsigned)c, vb);
            }
        }
        return;
    }

    // ---- GEMM path: h[n][o] = sum_k seq[n][k]*W[o][k], bf16-in fp32-acc ----
    const int base = (blockIdx.x - NCHUNK) * 64;
#define BS_OFF 16384

    // stage Bs: W[o][k] fp32 -> bf16, swizzled. thread: o=t>>1, 64 k's.
    {
        const int o = t >> 1, ksb = (t & 1) * 64;
        const float4* Wr = (const float4*)(W + o * 128 + ksb);
#pragma unroll
        for (int i = 0; i < 16; i += 2) {
            float4 x = Wr[i], y = Wr[i + 1];
            uint4 p;
            p.x = f2bf(x.x) | (f2bf(x.y) << 16);
            p.y = f2bf(x.z) | (f2bf(x.w) << 16);
            p.z = f2bf(y.x) | (f2bf(y.y) << 16);
            p.w = f2bf(y.z) | (f2bf(y.w) << 16);
            int byte = o * 256 + (ksb + i * 4) * 2;
            *(uint4*)(lds + BS_OFF + (byte ^ ((o & 7) << 4))) = p;
        }
    }
    // stage As: seq rows [base..base+64) fp32 -> bf16, swizzled.
    {
        const int row = t >> 2, n = base + row;
        const int c0 = (t & 3) * 4;
        const float4* Sr = (const float4*)(seq + (size_t)n * 128);
        const bool ok = (n < NN);
#pragma unroll
        for (int i = 0; i < 4; ++i) {
            int cc = c0 + i;
            float4 x = ok ? Sr[cc * 2]     : make_float4(0.f, 0.f, 0.f, 0.f);
            float4 y = ok ? Sr[cc * 2 + 1] : make_float4(0.f, 0.f, 0.f, 0.f);
            uint4 p;
            p.x = f2bf(x.x) | (f2bf(x.y) << 16);
            p.y = f2bf(x.z) | (f2bf(x.w) << 16);
            p.z = f2bf(y.x) | (f2bf(y.y) << 16);
            p.w = f2bf(y.z) | (f2bf(y.w) << 16);
            int byte = row * 256 + cc * 16;
            *(uint4*)(lds + (byte ^ ((row & 7) << 4))) = p;
        }
    }
    __syncthreads();

    const int l = t & 63, wv = t >> 6;
    const int lr = l & 15, kg = l >> 4;
    const int arow = wv * 16 + lr;
    f32x4 acc[8] = {};

#pragma unroll
    for (int ks = 0; ks < 4; ++ks) {
        const int kbyte = ks * 64 + kg * 16;
        short8 av = *(short8*)(lds + ((arow * 256 + kbyte) ^ ((arow & 7) << 4)));
#pragma unroll
        for (int c = 0; c < 8; ++c) {
            const int o = c * 16 + lr;
            short8 bv = *(short8*)(lds + BS_OFF +
                                   ((o * 256 + kbyte) ^ ((o & 7) << 4)));
            acc[c] = __builtin_amdgcn_mfma_f32_16x16x32_bf16(av, bv, acc[c], 0, 0, 0);
        }
    }

#pragma unroll
    for (int c = 0; c < 8; ++c) {
#pragma unroll
        for (int r = 0; r < 4; ++r) {
            int n = base + wv * 16 + kg * 4 + r;
            if (n < NN)
                h[(size_t)n * DD + c * 16 + lr] = (unsigned short)f2bf(acc[c][r]);
        }
    }
}

// ============ K2: fused fill(LDS) + gather, one block per 64-row bucket ======
// 512 threads = 8 waves. Phase A: hist/scan/reorder bucket edges into LDS recs.
// Phase B: wave w gathers rows w*8..w*8+7, 4 edge slots x 16 lanes each.
__global__ __launch_bounds__(512) void k2_fill_gather(
        const unsigned short* __restrict__ h,
        const uint2* __restrict__ ebin,
        const int* __restrict__ gcur,
        const float* __restrict__ bias,
        float* __restrict__ out) {
    __shared__ unsigned int recs[ECAP];    // 8 KB: (val_bf16<<16 | col)
    __shared__ int lh[BROWS];
    __shared__ int rend[BROWS];            // inclusive per-row ends
    __shared__ int rcur[BROWS];
    const int k = blockIdx.x, t = threadIdx.x;
    const int wid = t >> 6, lane = t & 63;

    int cnt = gcur[k];
    if (cnt > ECAP) cnt = ECAP;
    const uint2* eb = ebin + (size_t)k * ECAP;

    if (t < BROWS) lh[t] = 0;
    __syncthreads();
    for (int e = t; e < cnt; e += 512)
        atomicAdd(&lh[(eb[e].x >> 16) & (BROWS - 1)], 1);
    __syncthreads();
    if (t < BROWS) {                       // wave-0 inclusive scan over 64
        int x = lh[t];
#pragma unroll
        for (int off = 1; off < 64; off <<= 1) {
            int y = __shfl_up(x, off);
            if (lane >= off) x += y;
        }
        rend[t] = x;
        rcur[t] = x - lh[t];
    }
    __syncthreads();
    for (int e = t; e < cnt; e += 512) {
        uint2 ed = eb[e];
        int row = (ed.x >> 16) & (BROWS - 1);
        int pos = atomicAdd(&rcur[row], 1);
        recs[pos] = (ed.x & 0xffffu) | (f2bf(__uint_as_float(ed.y)) << 16);
    }
    __syncthreads();

    // ---- Phase B: gather ----
    const int slot = lane >> 4;
    const int sub  = lane & 15;
    const unsigned short* hp = h + sub * 8;
    const float4* b4 = (const float4*)(bias + sub * 8);
    const float4 b0 = b4[0], b1 = b4[1];

#define BODY(EE) do {                                                          \
        unsigned int cv = recs[EE];                                            \
        float v = __uint_as_float(cv & 0xffff0000u);                           \
        uint4 hv = *(const uint4*)(hp + (size_t)(cv & 0xffffu) * DD);          \
        unsigned int uu;                                                       \
        uu = hv.x;                                                             \
        acc[0] = fmaf(v, __uint_as_float(uu << 16),          acc[0]);          \
        acc[1] = fmaf(v, __uint_as_float(uu & 0xffff0000u),  acc[1]);          \
        uu = hv.y;                                                             \
        acc[2] = fmaf(v, __uint_as_float(uu << 16),          acc[2]);          \
        acc[3] = fmaf(v, __uint_as_float(uu & 0xffff0000u),  acc[3]);          \
        uu = hv.z;                                                             \
        acc[4] = fmaf(v, __uint_as_float(uu << 16),          acc[4]);          \
        acc[5] = fmaf(v, __uint_as_float(uu & 0xffff0000u),  acc[5]);          \
        uu = hv.w;                                                             \
        acc[6] = fmaf(v, __uint_as_float(uu << 16),          acc[6]);          \
        acc[7] = fmaf(v, __uint_as_float(uu & 0xffff0000u),  acc[7]);          \
    } while (0)

#pragma unroll 1
    for (int ri = 0; ri < 8; ++ri) {
        const int row = wid * 8 + ri;
        const int begin = row ? rend[row - 1] : 0;
        const int e1 = rend[row];
        float acc[8] = {0.f, 0.f, 0.f, 0.f, 0.f, 0.f, 0.f, 0.f};

        int e = begin + slot;
        for (; e + 12 < e1; e += 16) { BODY(e); BODY(e + 4); BODY(e + 8); BODY(e + 12); }
        for (; e < e1; e += 4) BODY(e);

#pragma unroll
        for (int i = 0; i < 8; ++i) {
            acc[i] += __shfl_xor(acc[i], 16);
            acc[i] += __shfl_xor(acc[i], 32);
        }

        if (slot == 0) {
            const int n = (k << BK_SHIFT) + row;
            if (n < NN) {
                f32x4 o0, o1;
                o0.x = fmaxf(acc[0] + b0.x, 0.f);
                o0.y = fmaxf(acc[1] + b0.y, 0.f);
                o0.z = fmaxf(acc[2] + b0.z, 0.f);
                o0.w = fmaxf(acc[3] + b0.w, 0.f);
                o1.x = fmaxf(acc[4] + b1.x, 0.f);
                o1.y = fmaxf(acc[5] + b1.y, 0.f);
                o1.z = fmaxf(acc[6] + b1.z, 0.f);
                o1.w = fmaxf(acc[7] + b1.w, 0.f);
                f32x4* op = (f32x4*)(out + (size_t)n * DD + sub * 8);
                __builtin_nontemporal_store(o0, op);
                __builtin_nontemporal_store(o1, op + 1);
            }
        }
    }
#undef BODY
}

extern "C" void kernel_launch(void* const* d_in, const int* in_sizes, int n_in,
                              void* d_out, int out_size, void* d_ws, size_t ws_size,
                              hipStream_t stream) {
    const float* seq  = (const float*)d_in[0];
    const float* W    = (const float*)d_in[1];
    const float* b    = (const float*)d_in[2];
    const int*   erow = (const int*)d_in[3];
    const int*   ecol = (const int*)d_in[4];
    const float* eval = (const float*)d_in[5];
    float* out = (float*)d_out;

    float* wsf = (float*)d_ws;
    unsigned short* h = (unsigned short*)(wsf + OFF_H);
    uint2* ebin = (uint2*)(wsf + OFF_EBIN);
    int*   gcur = (int*)(wsf + OFF_CUR);

    hipMemsetAsync(gcur, 0, NBUCK * sizeof(int), stream);
    k1_scatter_gemm<<<NCHUNK + NGB, 256, 0, stream>>>(seq, W, h, erow, ecol,
                                                      eval, gcur, ebin);
    k2_fill_gather<<<NBUCK, 512, 0, stream>>>(h, ebin, gcur, b, out);
}

// Round 18
// 74.844 us; speedup vs baseline: 1.1342x; 1.1342x over previous
//
#include <hip/hip_runtime.h>

#define NN 50000
#define NE 800000
#define DD 128

#define BK_SHIFT 6                 // 64 rows per bucket
#define BROWS 64
#define NBUCK 782                  // ceil(50000/64)
#define ECAP 2048                  // mean fill 1023, sigma ~32
#define CHUNK 2048
#define NCHUNK 391                 // ceil(800000/2048)
#define NGB 782                    // ceil(50000/64) gemm blocks

// ---------------- ws layout (float units) ----------------
#define OFF_H      0               // NN*DD bf16 = 3,200,000 floats
#define OFF_EBIN   3200000         // NBUCK*ECAP uint2 = 3,203,072 floats
#define OFF_CUR    6403072         // NBUCK ints
#define WS_FULL_FLOATS 6403854     // ~25.6 MB

typedef short short8 __attribute__((ext_vector_type(8)));
typedef float f32x4 __attribute__((ext_vector_type(4)));

static __device__ __forceinline__ unsigned int f2bf(float x) {
    unsigned int u = __float_as_uint(x);
    return (u + 0x7fffu + ((u >> 16) & 1u)) >> 16;  // RNE
}

// ============ K1: edge scatter (blocks 0..390, first) || MFMA GEMM (rest) ====
__global__ __launch_bounds__(256) void k1_scatter_gemm(
        const float* __restrict__ seq, const float* __restrict__ W,
        unsigned short* __restrict__ h,
        const int* __restrict__ erow, const int* __restrict__ ecol,
        const float* __restrict__ eval,
        int* __restrict__ gcur, uint2* __restrict__ ebin) {
    __shared__ uint4 lds4[3072];           // 48 KB
    char* lds = (char*)lds4;
    const int t = threadIdx.x;

    if (blockIdx.x < NCHUNK) {
        // ---- scatter: LDS hist -> global bump-reserve -> contiguous runs ----
        int* lh = (int*)lds4;              // [NBUCK] count, then cursor
        for (int i = t; i < NBUCK; i += 256) lh[i] = 0;
        __syncthreads();
        const int e0 = blockIdx.x * CHUNK;
        for (int i = t; i < CHUNK; i += 256) {
            int e = e0 + i;
            if (e < NE) atomicAdd(&lh[erow[e] >> BK_SHIFT], 1);
        }
        __syncthreads();
        for (int i = t; i < NBUCK; i += 256) {
            int c = lh[i];
            lh[i] = c ? atomicAdd(&gcur[i], c) : 0;   // count -> bucket-local base
        }
        __syncthreads();
        for (int i = t; i < CHUNK; i += 256) {
            int e = e0 + i;
            if (e < NE) {
                int r = erow[e], c = ecol[e];
                unsigned int vb = __float_as_uint(eval[e]);
                int k = r >> BK_SHIFT;
                int pos = atomicAdd(&lh[k], 1);
                if (pos < ECAP)
                    ebin[(size_t)k * ECAP + pos] =
                        make_uint2(((unsigned)r << 16) | (unsigned)c, vb);
            }
        }
        return;
    }

    // ---- GEMM path: h[n][o] = sum_k seq[n][k]*W[o][k], bf16-in fp32-acc ----
    const int base = (blockIdx.x - NCHUNK) * 64;
#define BS_OFF 16384

    // stage Bs: W[o][k] fp32 -> bf16, swizzled. thread: o=t>>1, 64 k's.
    {
        const int o = t >> 1, ksb = (t & 1) * 64;
        const float4* Wr = (const float4*)(W + o * 128 + ksb);
#pragma unroll
        for (int i = 0; i < 16; i += 2) {
            float4 x = Wr[i], y = Wr[i + 1];
            uint4 p;
            p.x = f2bf(x.x) | (f2bf(x.y) << 16);
            p.y = f2bf(x.z) | (f2bf(x.w) << 16);
            p.z = f2bf(y.x) | (f2bf(y.y) << 16);
            p.w = f2bf(y.z) | (f2bf(y.w) << 16);
            int byte = o * 256 + (ksb + i * 4) * 2;
            *(uint4*)(lds + BS_OFF + (byte ^ ((o & 7) << 4))) = p;
        }
    }
    // stage As: seq rows [base..base+64) fp32 -> bf16, swizzled.
    {
        const int row = t >> 2, n = base + row;
        const int c0 = (t & 3) * 4;
        const float4* Sr = (const float4*)(seq + (size_t)n * 128);
        const bool ok = (n < NN);
#pragma unroll
        for (int i = 0; i < 4; ++i) {
            int cc = c0 + i;
            float4 x = ok ? Sr[cc * 2]     : make_float4(0.f, 0.f, 0.f, 0.f);
            float4 y = ok ? Sr[cc * 2 + 1] : make_float4(0.f, 0.f, 0.f, 0.f);
            uint4 p;
            p.x = f2bf(x.x) | (f2bf(x.y) << 16);
            p.y = f2bf(x.z) | (f2bf(x.w) << 16);
            p.z = f2bf(y.x) | (f2bf(y.y) << 16);
            p.w = f2bf(y.z) | (f2bf(y.w) << 16);
            int byte = row * 256 + cc * 16;
            *(uint4*)(lds + (byte ^ ((row & 7) << 4))) = p;
        }
    }
    __syncthreads();

    const int l = t & 63, wv = t >> 6;
    const int lr = l & 15, kg = l >> 4;
    const int arow = wv * 16 + lr;
    f32x4 acc[8] = {};

#pragma unroll
    for (int ks = 0; ks < 4; ++ks) {
        const int kbyte = ks * 64 + kg * 16;
        short8 av = *(short8*)(lds + ((arow * 256 + kbyte) ^ ((arow & 7) << 4)));
#pragma unroll
        for (int c = 0; c < 8; ++c) {
            const int o = c * 16 + lr;
            short8 bv = *(short8*)(lds + BS_OFF +
                                   ((o * 256 + kbyte) ^ ((o & 7) << 4)));
            acc[c] = __builtin_amdgcn_mfma_f32_16x16x32_bf16(av, bv, acc[c], 0, 0, 0);
        }
    }

#pragma unroll
    for (int c = 0; c < 8; ++c) {
#pragma unroll
        for (int r = 0; r < 4; ++r) {
            int n = base + wv * 16 + kg * 4 + r;
            if (n < NN)
                h[(size_t)n * DD + c * 16 + lr] = (unsigned short)f2bf(acc[c][r]);
        }
    }
}

// ============ K2: fused fill(LDS) + gather, one block per 64-row bucket ======
// 512 threads = 8 waves. Phase A: hist/scan/reorder bucket edges into LDS recs.
// Phase B: wave w gathers rows w*8..w*8+7, 4 edge slots x 16 lanes each.
__global__ __launch_bounds__(512) void k2_fill_gather(
        const unsigned short* __restrict__ h,
        const uint2* __restrict__ ebin,
        const int* __restrict__ gcur,
        const float* __restrict__ bias,
        float* __restrict__ out) {
    __shared__ unsigned int recs[ECAP];    // 8 KB: (val_bf16<<16 | col)
    __shared__ int lh[BROWS];
    __shared__ int rend[BROWS];            // inclusive per-row ends
    __shared__ int rcur[BROWS];
    const int k = blockIdx.x, t = threadIdx.x;
    const int wid = t >> 6, lane = t & 63;

    int cnt = gcur[k];
    if (cnt > ECAP) cnt = ECAP;
    const uint2* eb = ebin + (size_t)k * ECAP;

    if (t < BROWS) lh[t] = 0;
    __syncthreads();
    for (int e = t; e < cnt; e += 512)
        atomicAdd(&lh[(eb[e].x >> 16) & (BROWS - 1)], 1);
    __syncthreads();
    if (t < BROWS) {                       // wave-0 inclusive scan over 64
        int x = lh[t];
#pragma unroll
        for (int off = 1; off < 64; off <<= 1) {
            int y = __shfl_up(x, off);
            if (lane >= off) x += y;
        }
        rend[t] = x;
        rcur[t] = x - lh[t];
    }
    __syncthreads();
    for (int e = t; e < cnt; e += 512) {
        uint2 ed = eb[e];
        int row = (ed.x >> 16) & (BROWS - 1);
        int pos = atomicAdd(&rcur[row], 1);
        recs[pos] = (ed.x & 0xffffu) | (f2bf(__uint_as_float(ed.y)) << 16);
    }
    __syncthreads();

    // ---- Phase B: gather ----
    const int slot = lane >> 4;
    const int sub  = lane & 15;
    const unsigned short* hp = h + sub * 8;
    const float4* b4 = (const float4*)(bias + sub * 8);
    const float4 b0 = b4[0], b1 = b4[1];

#define BODY(EE) do {                                                          \
        unsigned int cv = recs[EE];                                            \
        float v = __uint_as_float(cv & 0xffff0000u);                           \
        uint4 hv = *(const uint4*)(hp + (size_t)(cv & 0xffffu) * DD);          \
        unsigned int uu;                                                       \
        uu = hv.x;                                                             \
        acc[0] = fmaf(v, __uint_as_float(uu << 16),          acc[0]);          \
        acc[1] = fmaf(v, __uint_as_float(uu & 0xffff0000u),  acc[1]);          \
        uu = hv.y;                                                             \
        acc[2] = fmaf(v, __uint_as_float(uu << 16),          acc[2]);          \
        acc[3] = fmaf(v, __uint_as_float(uu & 0xffff0000u),  acc[3]);          \
        uu = hv.z;                                                             \
        acc[4] = fmaf(v, __uint_as_float(uu << 16),          acc[4]);          \
        acc[5] = fmaf(v, __uint_as_float(uu & 0xffff0000u),  acc[5]);          \
        uu = hv.w;                                                             \
        acc[6] = fmaf(v, __uint_as_float(uu << 16),          acc[6]);          \
        acc[7] = fmaf(v, __uint_as_float(uu & 0xffff0000u),  acc[7]);          \
    } while (0)

#pragma unroll 1
    for (int ri = 0; ri < 8; ++ri) {
        const int row = wid * 8 + ri;
        const int begin = row ? rend[row - 1] : 0;
        const int e1 = rend[row];
        float acc[8] = {0.f, 0.f, 0.f, 0.f, 0.f, 0.f, 0.f, 0.f};

        int e = begin + slot;
        for (; e + 12 < e1; e += 16) { BODY(e); BODY(e + 4); BODY(e + 8); BODY(e + 12); }
        for (; e < e1; e += 4) BODY(e);

#pragma unroll
        for (int i = 0; i < 8; ++i) {
            acc[i] += __shfl_xor(acc[i], 16);
            acc[i] += __shfl_xor(acc[i], 32);
        }

        if (slot == 0) {
            const int n = (k << BK_SHIFT) + row;
            if (n < NN) {
                f32x4 o0, o1;
                o0.x = fmaxf(acc[0] + b0.x, 0.f);
                o0.y = fmaxf(acc[1] + b0.y, 0.f);
                o0.z = fmaxf(acc[2] + b0.z, 0.f);
                o0.w = fmaxf(acc[3] + b0.w, 0.f);
                o1.x = fmaxf(acc[4] + b1.x, 0.f);
                o1.y = fmaxf(acc[5] + b1.y, 0.f);
                o1.z = fmaxf(acc[6] + b1.z, 0.f);
                o1.w = fmaxf(acc[7] + b1.w, 0.f);
                f32x4* op = (f32x4*)(out + (size_t)n * DD + sub * 8);
                __builtin_nontemporal_store(o0, op);
                __builtin_nontemporal_store(o1, op + 1);
            }
        }
    }
#undef BODY
}

extern "C" void kernel_launch(void* const* d_in, const int* in_sizes, int n_in,
                              void* d_out, int out_size, void* d_ws, size_t ws_size,
                              hipStream_t stream) {
    const float* seq  = (const float*)d_in[0];
    const float* W    = (const float*)d_in[1];
    const float* b    = (const float*)d_in[2];
    const int*   erow = (const int*)d_in[3];
    const int*   ecol = (const int*)d_in[4];
    const float* eval = (const float*)d_in[5];
    float* out = (float*)d_out;

    float* wsf = (float*)d_ws;
    unsigned short* h = (unsigned short*)(wsf + OFF_H);
    uint2* ebin = (uint2*)(wsf + OFF_EBIN);
    int*   gcur = (int*)(wsf + OFF_CUR);

    hipMemsetAsync(gcur, 0, NBUCK * sizeof(int), stream);
    k1_scatter_gemm<<<NCHUNK + NGB, 256, 0, stream>>>(seq, W, h, erow, ecol,
                                                      eval, gcur, ebin);
    k2_fill_gather<<<NBUCK, 512, 0, stream>>>(h, ebin, gcur, b, out);
}

// Round 19
// 71.854 us; speedup vs baseline: 1.1813x; 1.0416x over previous
//
#include <hip/hip_runtime.h>

#define NN 50000
#define NE 800000
#define DD 128

#define BK_SHIFT 8                 // coarse bucket = row >> 8 (256 rows)
#define NBUCK 196                  // coarse buckets
#define ECAP 8192                  // entries per coarse bucket (mean 4081)
#define CHUNK 2048
#define NCHUNK 391                 // ceil(800000/2048)
#define NGB 782                    // ceil(50000/64) gemm blocks
#define BROWS 64                   // rows per K2 slice block
#define RCAP 2048                  // recs capacity per slice (mean 1024)

// ---------------- ws layout (float units) ----------------
#define OFF_H      0               // NN*DD bf16 = 3,200,000 floats
#define OFF_EBIN   3200000         // NBUCK*ECAP uint2 = 3,211,264 floats
#define OFF_CUR    6411264         // NBUCK ints
#define WS_FULL_FLOATS 6411460     // ~25.6 MB

typedef short short8 __attribute__((ext_vector_type(8)));
typedef float f32x4 __attribute__((ext_vector_type(4)));

static __device__ __forceinline__ unsigned int f2bf(float x) {
    unsigned int u = __float_as_uint(x);
    return (u + 0x7fffu + ((u >> 16) & 1u)) >> 16;  // RNE
}

// ============ K1: edge scatter (blocks 0..390, first) || MFMA GEMM (rest) ====
__global__ __launch_bounds__(256) void k1_scatter_gemm(
        const float* __restrict__ seq, const float* __restrict__ W,
        unsigned short* __restrict__ h,
        const int* __restrict__ erow, const int* __restrict__ ecol,
        const float* __restrict__ eval,
        int* __restrict__ gcur, uint2* __restrict__ ebin) {
    __shared__ uint4 lds4[3072];           // 48 KB
    char* lds = (char*)lds4;
    const int t = threadIdx.x;

    if (blockIdx.x < NCHUNK) {
        // ---- scatter: LDS hist (196) -> global bump-reserve -> runs ~10.4 ----
        int* lh = (int*)lds4;
        for (int i = t; i < NBUCK; i += 256) lh[i] = 0;
        __syncthreads();
        const int e0 = blockIdx.x * CHUNK;
        for (int i = t; i < CHUNK; i += 256) {
            int e = e0 + i;
            if (e < NE) atomicAdd(&lh[erow[e] >> BK_SHIFT], 1);
        }
        __syncthreads();
        for (int i = t; i < NBUCK; i += 256) {
            int c = lh[i];
            lh[i] = c ? atomicAdd(&gcur[i], c) : 0;   // count -> bucket-local base
        }
        __syncthreads();
        for (int i = t; i < CHUNK; i += 256) {
            int e = e0 + i;
            if (e < NE) {
                int r = erow[e], c = ecol[e];
                unsigned int vb = __float_as_uint(eval[e]);
                int k = r >> BK_SHIFT;
                int pos = atomicAdd(&lh[k], 1);
                if (pos < ECAP)
                    ebin[(size_t)k * ECAP + pos] =
                        make_uint2(((unsigned)r << 16) | (unsigned)c, vb);
            }
        }
        return;
    }

    // ---- GEMM path: h[n][o] = sum_k seq[n][k]*W[o][k], bf16-in fp32-acc ----
    const int base = (blockIdx.x - NCHUNK) * 64;
#define BS_OFF 16384

    // stage Bs: W[o][k] fp32 -> bf16, swizzled. thread: o=t>>1, 64 k's.
    {
        const int o = t >> 1, ksb = (t & 1) * 64;
        const float4* Wr = (const float4*)(W + o * 128 + ksb);
#pragma unroll
        for (int i = 0; i < 16; i += 2) {
            float4 x = Wr[i], y = Wr[i + 1];
            uint4 p;
            p.x = f2bf(x.x) | (f2bf(x.y) << 16);
            p.y = f2bf(x.z) | (f2bf(x.w) << 16);
            p.z = f2bf(y.x) | (f2bf(y.y) << 16);
            p.w = f2bf(y.z) | (f2bf(y.w) << 16);
            int byte = o * 256 + (ksb + i * 4) * 2;
            *(uint4*)(lds + BS_OFF + (byte ^ ((o & 7) << 4))) = p;
        }
    }
    // stage As: seq rows [base..base+64) fp32 -> bf16, swizzled.
    {
        const int row = t >> 2, n = base + row;
        const int c0 = (t & 3) * 4;
        const float4* Sr = (const float4*)(seq + (size_t)n * 128);
        const bool ok = (n < NN);
#pragma unroll
        for (int i = 0; i < 4; ++i) {
            int cc = c0 + i;
            float4 x = ok ? Sr[cc * 2]     : make_float4(0.f, 0.f, 0.f, 0.f);
            float4 y = ok ? Sr[cc * 2 + 1] : make_float4(0.f, 0.f, 0.f, 0.f);
            uint4 p;
            p.x = f2bf(x.x) | (f2bf(x.y) << 16);
            p.y = f2bf(x.z) | (f2bf(x.w) << 16);
            p.z = f2bf(y.x) | (f2bf(y.y) << 16);
            p.w = f2bf(y.z) | (f2bf(y.w) << 16);
            int byte = row * 256 + cc * 16;
            *(uint4*)(lds + (byte ^ ((row & 7) << 4))) = p;
        }
    }
    __syncthreads();

    const int l = t & 63, wv = t >> 6;
    const int lr = l & 15, kg = l >> 4;
    const int arow = wv * 16 + lr;
    f32x4 acc[8] = {};

#pragma unroll
    for (int ks = 0; ks < 4; ++ks) {
        const int kbyte = ks * 64 + kg * 16;
        short8 av = *(short8*)(lds + ((arow * 256 + kbyte) ^ ((arow & 7) << 4)));
#pragma unroll
        for (int c = 0; c < 8; ++c) {
            const int o = c * 16 + lr;
            short8 bv = *(short8*)(lds + BS_OFF +
                                   ((o * 256 + kbyte) ^ ((o & 7) << 4)));
            acc[c] = __builtin_amdgcn_mfma_f32_16x16x32_bf16(av, bv, acc[c], 0, 0, 0);
        }
    }

#pragma unroll
    for (int c = 0; c < 8; ++c) {
#pragma unroll
        for (int r = 0; r < 4; ++r) {
            int n = base + wv * 16 + kg * 4 + r;
            if (n < NN)
                h[(size_t)n * DD + c * 16 + lr] = (unsigned short)f2bf(acc[c][r]);
        }
    }
}

// ============ K2: sliced fill(LDS) + gather, 4 blocks per coarse bucket ======
// Block b: coarse bucket b>>2, row slice (b&3)*64..+64. 512 threads = 8 waves.
// Phase A: stream coarse ebin twice (hist, reorder), keep in-slice entries.
// Phase B: wave w gathers rows w*8..w*8+7, 4 edge slots x 16 lanes each.
__global__ __launch_bounds__(512) void k2_fill_gather(
        const unsigned short* __restrict__ h,
        const uint2* __restrict__ ebin,
        const int* __restrict__ gcur,
        const float* __restrict__ bias,
        float* __restrict__ out) {
    __shared__ unsigned int recs[RCAP];    // 8 KB: (val_bf16<<16 | col)
    __shared__ int lh[BROWS];
    __shared__ int rend[BROWS];            // inclusive per-row ends
    __shared__ int rcur[BROWS];
    const int t = threadIdx.x;
    const int kc = blockIdx.x >> 2;        // coarse bucket
    const int s  = blockIdx.x & 3;         // slice
    const int wid = t >> 6, lane = t & 63;

    int cnt = gcur[kc];
    if (cnt > ECAP) cnt = ECAP;
    const uint2* eb = ebin + (size_t)kc * ECAP;

    if (t < BROWS) lh[t] = 0;
    __syncthreads();
    for (int e = t; e < cnt; e += 512) {
        int row = (int)(eb[e].x >> 16);
        if (((row >> 6) & 3) == s) atomicAdd(&lh[row & (BROWS - 1)], 1);
    }
    __syncthreads();
    if (t < BROWS) {                       // wave-0 inclusive scan over 64
        int x = lh[t];
#pragma unroll
        for (int off = 1; off < 64; off <<= 1) {
            int y = __shfl_up(x, off);
            if (lane >= off) x += y;
        }
        if (x > RCAP) x = RCAP;
        rend[t] = x;
        rcur[t] = x - lh[t];
    }
    __syncthreads();
    for (int e = t; e < cnt; e += 512) {
        uint2 ed = eb[e];
        int row = (int)(ed.x >> 16);
        if (((row >> 6) & 3) == s) {
            int pos = atomicAdd(&rcur[row & (BROWS - 1)], 1);
            if (pos < RCAP)
                recs[pos] = (ed.x & 0xffffu) | (f2bf(__uint_as_float(ed.y)) << 16);
        }
    }
    __syncthreads();

    // ---- Phase B: gather ----
    const int slot = lane >> 4;
    const int sub  = lane & 15;
    const unsigned short* hp = h + sub * 8;
    const float4* b4 = (const float4*)(bias + sub * 8);
    const float4 b0 = b4[0], b1 = b4[1];

#define BODY(EE) do {                                                          \
        unsigned int cv = recs[EE];                                            \
        float v = __uint_as_float(cv & 0xffff0000u);                           \
        uint4 hv = *(const uint4*)(hp + (size_t)(cv & 0xffffu) * DD);          \
        unsigned int uu;                                                       \
        uu = hv.x;                                                             \
        acc[0] = fmaf(v, __uint_as_float(uu << 16),          acc[0]);          \
        acc[1] = fmaf(v, __uint_as_float(uu & 0xffff0000u),  acc[1]);          \
        uu = hv.y;                                                             \
        acc[2] = fmaf(v, __uint_as_float(uu << 16),          acc[2]);          \
        acc[3] = fmaf(v, __uint_as_float(uu & 0xffff0000u),  acc[3]);          \
        uu = hv.z;                                                             \
        acc[4] = fmaf(v, __uint_as_float(uu << 16),          acc[4]);          \
        acc[5] = fmaf(v, __uint_as_float(uu & 0xffff0000u),  acc[5]);          \
        uu = hv.w;                                                             \
        acc[6] = fmaf(v, __uint_as_float(uu << 16),          acc[6]);          \
        acc[7] = fmaf(v, __uint_as_float(uu & 0xffff0000u),  acc[7]);          \
    } while (0)

#pragma unroll 1
    for (int ri = 0; ri < 8; ++ri) {
        const int row = wid * 8 + ri;
        const int begin = row ? rend[row - 1] : 0;
        const int e1 = rend[row];
        float acc[8] = {0.f, 0.f, 0.f, 0.f, 0.f, 0.f, 0.f, 0.f};

        int e = begin + slot;
        for (; e + 12 < e1; e += 16) { BODY(e); BODY(e + 4); BODY(e + 8); BODY(e + 12); }
        for (; e < e1; e += 4) BODY(e);

#pragma unroll
        for (int i = 0; i < 8; ++i) {
            acc[i] += __shfl_xor(acc[i], 16);
            acc[i] += __shfl_xor(acc[i], 32);
        }

        if (slot == 0) {
            const int n = blockIdx.x * BROWS + row;
            if (n < NN) {
                f32x4 o0, o1;
                o0.x = fmaxf(acc[0] + b0.x, 0.f);
                o0.y = fmaxf(acc[1] + b0.y, 0.f);
                o0.z = fmaxf(acc[2] + b0.z, 0.f);
                o0.w = fmaxf(acc[3] + b0.w, 0.f);
                o1.x = fmaxf(acc[4] + b1.x, 0.f);
                o1.y = fmaxf(acc[5] + b1.y, 0.f);
                o1.z = fmaxf(acc[6] + b1.z, 0.f);
                o1.w = fmaxf(acc[7] + b1.w, 0.f);
                f32x4* op = (f32x4*)(out + (size_t)n * DD + sub * 8);
                __builtin_nontemporal_store(o0, op);
                __builtin_nontemporal_store(o1, op + 1);
            }
        }
    }
#undef BODY
}

extern "C" void kernel_launch(void* const* d_in, const int* in_sizes, int n_in,
                              void* d_out, int out_size, void* d_ws, size_t ws_size,
                              hipStream_t stream) {
    const float* seq  = (const float*)d_in[0];
    const float* W    = (const float*)d_in[1];
    const float* b    = (const float*)d_in[2];
    const int*   erow = (const int*)d_in[3];
    const int*   ecol = (const int*)d_in[4];
    const float* eval = (const float*)d_in[5];
    float* out = (float*)d_out;

    float* wsf = (float*)d_ws;
    unsigned short* h = (unsigned short*)(wsf + OFF_H);
    uint2* ebin = (uint2*)(wsf + OFF_EBIN);
    int*   gcur = (int*)(wsf + OFF_CUR);

    hipMemsetAsync(gcur, 0, NBUCK * sizeof(int), stream);
    k1_scatter_gemm<<<NCHUNK + NGB, 256, 0, stream>>>(seq, W, h, erow, ecol,
                                                      eval, gcur, ebin);
    k2_fill_gather<<<NBUCK * 4, 512, 0, stream>>>(h, ebin, gcur, b, out);
}

// Round 20
// 69.622 us; speedup vs baseline: 1.2192x; 1.0321x over previous
//
#include <hip/hip_runtime.h>

#define NN 50000
#define NE 800000
#define DD 128

#define BK_SHIFT 8                 // coarse bucket = row >> 8 (256 rows)
#define NBUCK 196                  // coarse buckets
#define ECAP 8192                  // entries per coarse bucket (mean 4081)
#define CHUNK 4096
#define NCHUNK 196                 // ceil(800000/4096)
#define EPT 16                     // edges per thread in scatter (CHUNK/256)
#define NGB 782                    // ceil(50000/64) gemm blocks
#define BROWS 64                   // rows per K2 slice block
#define RCAP 2048                  // recs capacity per slice (mean 1024)

// ---------------- ws layout (float units) ----------------
#define OFF_H      0               // NN*DD bf16 = 3,200,000 floats
#define OFF_EBIN   3200000         // NBUCK*ECAP uint2 = 3,211,264 floats
#define OFF_CUR    6411264         // NBUCK ints
#define WS_FULL_FLOATS 6411460     // ~25.6 MB

typedef short short8 __attribute__((ext_vector_type(8)));
typedef float f32x4 __attribute__((ext_vector_type(4)));

static __device__ __forceinline__ unsigned int f2bf(float x) {
    unsigned int u = __float_as_uint(x);
    return (u + 0x7fffu + ((u >> 16) & 1u)) >> 16;  // RNE
}

// ============ K1: edge scatter (blocks 0..195, first) || MFMA GEMM (rest) ====
__global__ __launch_bounds__(256) void k1_scatter_gemm(
        const float* __restrict__ seq, const float* __restrict__ W,
        unsigned short* __restrict__ h,
        const int* __restrict__ erow, const int* __restrict__ ecol,
        const float* __restrict__ eval,
        int* __restrict__ gcur, uint2* __restrict__ ebin) {
    __shared__ uint4 lds4[3072];           // 48 KB
    char* lds = (char*)lds4;
    const int t = threadIdx.x;

    if (blockIdx.x < NCHUNK) {
        // ---- scatter: LDS hist -> global bump-reserve -> runs ~20.9 ----
        int* lh = (int*)lds4;
        int rbuf[EPT];
        for (int i = t; i < NBUCK; i += 256) lh[i] = 0;
        __syncthreads();
        const int e0 = blockIdx.x * CHUNK;
#pragma unroll
        for (int j = 0; j < EPT; ++j) {
            int e = e0 + j * 256 + t;
            rbuf[j] = (e < NE) ? erow[e] : -1;
            if (rbuf[j] >= 0) atomicAdd(&lh[rbuf[j] >> BK_SHIFT], 1);
        }
        __syncthreads();
        for (int i = t; i < NBUCK; i += 256) {
            int c = lh[i];
            lh[i] = c ? atomicAdd(&gcur[i], c) : 0;   // count -> bucket-local base
        }
        __syncthreads();
#pragma unroll
        for (int j = 0; j < EPT; ++j) {
            int r = rbuf[j];
            if (r >= 0) {
                int e = e0 + j * 256 + t;
                unsigned int vb = __float_as_uint(eval[e]);
                int c = ecol[e];
                int k = r >> BK_SHIFT;
                int pos = atomicAdd(&lh[k], 1);
                if (pos < ECAP)
                    ebin[(size_t)k * ECAP + pos] =
                        make_uint2(((unsigned)r << 16) | (unsigned)c, vb);
            }
        }
        return;
    }

    // ---- GEMM path: h[n][o] = sum_k seq[n][k]*W[o][k], bf16-in fp32-acc ----
    const int base = (blockIdx.x - NCHUNK) * 64;
#define BS_OFF 16384

    // stage Bs: W[o][k] fp32 -> bf16, swizzled. thread: o=t>>1, 64 k's.
    {
        const int o = t >> 1, ksb = (t & 1) * 64;
        const float4* Wr = (const float4*)(W + o * 128 + ksb);
#pragma unroll
        for (int i = 0; i < 16; i += 2) {
            float4 x = Wr[i], y = Wr[i + 1];
            uint4 p;
            p.x = f2bf(x.x) | (f2bf(x.y) << 16);
            p.y = f2bf(x.z) | (f2bf(x.w) << 16);
            p.z = f2bf(y.x) | (f2bf(y.y) << 16);
            p.w = f2bf(y.z) | (f2bf(y.w) << 16);
            int byte = o * 256 + (ksb + i * 4) * 2;
            *(uint4*)(lds + BS_OFF + (byte ^ ((o & 7) << 4))) = p;
        }
    }
    // stage As: seq rows [base..base+64) fp32 -> bf16, swizzled.
    {
        const int row = t >> 2, n = base + row;
        const int c0 = (t & 3) * 4;
        const float4* Sr = (const float4*)(seq + (size_t)n * 128);
        const bool ok = (n < NN);
#pragma unroll
        for (int i = 0; i < 4; ++i) {
            int cc = c0 + i;
            float4 x = ok ? Sr[cc * 2]     : make_float4(0.f, 0.f, 0.f, 0.f);
            float4 y = ok ? Sr[cc * 2 + 1] : make_float4(0.f, 0.f, 0.f, 0.f);
            uint4 p;
            p.x = f2bf(x.x) | (f2bf(x.y) << 16);
            p.y = f2bf(x.z) | (f2bf(x.w) << 16);
            p.z = f2bf(y.x) | (f2bf(y.y) << 16);
            p.w = f2bf(y.z) | (f2bf(y.w) << 16);
            int byte = row * 256 + cc * 16;
            *(uint4*)(lds + (byte ^ ((row & 7) << 4))) = p;
        }
    }
    __syncthreads();

    const int l = t & 63, wv = t >> 6;
    const int lr = l & 15, kg = l >> 4;
    const int arow = wv * 16 + lr;
    f32x4 acc[8] = {};

#pragma unroll
    for (int ks = 0; ks < 4; ++ks) {
        const int kbyte = ks * 64 + kg * 16;
        short8 av = *(short8*)(lds + ((arow * 256 + kbyte) ^ ((arow & 7) << 4)));
#pragma unroll
        for (int c = 0; c < 8; ++c) {
            const int o = c * 16 + lr;
            short8 bv = *(short8*)(lds + BS_OFF +
                                   ((o * 256 + kbyte) ^ ((o & 7) << 4)));
            acc[c] = __builtin_amdgcn_mfma_f32_16x16x32_bf16(av, bv, acc[c], 0, 0, 0);
        }
    }

#pragma unroll
    for (int c = 0; c < 8; ++c) {
#pragma unroll
        for (int r = 0; r < 4; ++r) {
            int n = base + wv * 16 + kg * 4 + r;
            if (n < NN)
                h[(size_t)n * DD + c * 16 + lr] = (unsigned short)f2bf(acc[c][r]);
        }
    }
}

// ============ K2: sliced fill(LDS, single ebin read) + gather ============
// Block b: coarse bucket b>>2, row slice (b&3)*64..+64. 512 threads = 8 waves.
// Phase A: ONE pass over coarse ebin -> LDS staging (ballot-aggregated append)
//          + 64-row hist; scan; LDS->LDS reorder into row-sorted recs.
// Phase B: wave w gathers rows w*8..w*8+7, 4 edge slots x 16 lanes each.
__global__ __launch_bounds__(512) void k2_fill_gather(
        const unsigned short* __restrict__ h,
        const uint2* __restrict__ ebin,
        const int* __restrict__ gcur,
        const float* __restrict__ bias,
        float* __restrict__ out) {
    __shared__ unsigned int recs[RCAP];     // 8 KB row-sorted (val_bf16<<16|col)
    __shared__ unsigned int rtmp[RCAP];     // 8 KB arrival-order recs
    __shared__ unsigned char rowb[RCAP];    // 2 KB row-in-slice per rtmp entry
    __shared__ int lh[BROWS];
    __shared__ int rend[BROWS];
    __shared__ int rcur[BROWS];
    __shared__ int tot;
    const int t = threadIdx.x;
    const int kc = blockIdx.x >> 2;        // coarse bucket
    const int s  = blockIdx.x & 3;         // slice
    const int wid = t >> 6, lane = t & 63;

    int cnt = gcur[kc];
    if (cnt > ECAP) cnt = ECAP;
    const uint2* eb = ebin + (size_t)kc * ECAP;

    if (t == 0) tot = 0;
    if (t < BROWS) lh[t] = 0;
    __syncthreads();

    for (int e0 = 0; e0 < cnt; e0 += 512) {
        int e = e0 + t;
        uint2 ed = (e < cnt) ? eb[e] : make_uint2(0u, 0u);
        int row = (int)(ed.x >> 16);
        bool ok = (e < cnt) && (((row >> 6) & 3) == s);
        unsigned long long m = __ballot(ok);
        int wcnt = __popcll(m);
        int b0 = 0;
        if (lane == 0 && wcnt) b0 = atomicAdd(&tot, wcnt);
        b0 = __shfl(b0, 0);
        if (ok) {
            int pos = b0 + __popcll(m & ((1ull << lane) - 1ull));
            int r6 = row & (BROWS - 1);
            if (pos < RCAP) {
                rtmp[pos] = (ed.x & 0xffffu) | (f2bf(__uint_as_float(ed.y)) << 16);
                rowb[pos] = (unsigned char)r6;
            }
            atomicAdd(&lh[r6], 1);
        }
    }
    __syncthreads();

    if (t < BROWS) {                       // wave-0 inclusive scan over 64
        int x = lh[t];
#pragma unroll
        for (int off = 1; off < 64; off <<= 1) {
            int y = __shfl_up(x, off);
            if (lane >= off) x += y;
        }
        if (x > RCAP) x = RCAP;
        rend[t] = x;
        rcur[t] = x - lh[t];
    }
    __syncthreads();

    int nt = tot < RCAP ? tot : RCAP;
    for (int i = t; i < nt; i += 512) {
        int r6 = rowb[i];
        int pos = atomicAdd(&rcur[r6], 1);
        if (pos < RCAP) recs[pos] = rtmp[i];
    }
    __syncthreads();

    // ---- Phase B: gather ----
    const int slot = lane >> 4;
    const int sub  = lane & 15;
    const unsigned short* hp = h + sub * 8;
    const float4* b4 = (const float4*)(bias + sub * 8);
    const float4 b0v = b4[0], b1v = b4[1];

#define BODY(EE) do {                                                          \
        unsigned int cv = recs[EE];                                            \
        float v = __uint_as_float(cv & 0xffff0000u);                           \
        uint4 hv = *(const uint4*)(hp + (size_t)(cv & 0xffffu) * DD);          \
        unsigned int uu;                                                       \
        uu = hv.x;                                                             \
        acc[0] = fmaf(v, __uint_as_float(uu << 16),          acc[0]);          \
        acc[1] = fmaf(v, __uint_as_float(uu & 0xffff0000u),  acc[1]);          \
        uu = hv.y;                                                             \
        acc[2] = fmaf(v, __uint_as_float(uu << 16),          acc[2]);          \
        acc[3] = fmaf(v, __uint_as_float(uu & 0xffff0000u),  acc[3]);          \
        uu = hv.z;                                                             \
        acc[4] = fmaf(v, __uint_as_float(uu << 16),          acc[4]);          \
        acc[5] = fmaf(v, __uint_as_float(uu & 0xffff0000u),  acc[5]);          \
        uu = hv.w;                                                             \
        acc[6] = fmaf(v, __uint_as_float(uu << 16),          acc[6]);          \
        acc[7] = fmaf(v, __uint_as_float(uu & 0xffff0000u),  acc[7]);          \
    } while (0)

#pragma unroll 1
    for (int ri = 0; ri < 8; ++ri) {
        const int row = wid * 8 + ri;
        const int begin = row ? rend[row - 1] : 0;
        const int e1 = rend[row];
        float acc[8] = {0.f, 0.f, 0.f, 0.f, 0.f, 0.f, 0.f, 0.f};

        int e = begin + slot;
        for (; e + 12 < e1; e += 16) { BODY(e); BODY(e + 4); BODY(e + 8); BODY(e + 12); }
        for (; e < e1; e += 4) BODY(e);

#pragma unroll
        for (int i = 0; i < 8; ++i) {
            acc[i] += __shfl_xor(acc[i], 16);
            acc[i] += __shfl_xor(acc[i], 32);
        }

        if (slot == 0) {
            const int n = blockIdx.x * BROWS + row;
            if (n < NN) {
                f32x4 o0, o1;
                o0.x = fmaxf(acc[0] + b0v.x, 0.f);
                o0.y = fmaxf(acc[1] + b0v.y, 0.f);
                o0.z = fmaxf(acc[2] + b0v.z, 0.f);
                o0.w = fmaxf(acc[3] + b0v.w, 0.f);
                o1.x = fmaxf(acc[4] + b1v.x, 0.f);
                o1.y = fmaxf(acc[5] + b1v.y, 0.f);
                o1.z = fmaxf(acc[6] + b1v.z, 0.f);
                o1.w = fmaxf(acc[7] + b1v.w, 0.f);
                f32x4* op = (f32x4*)(out + (size_t)n * DD + sub * 8);
                __builtin_nontemporal_store(o0, op);
                __builtin_nontemporal_store(o1, op + 1);
            }
        }
    }
#undef BODY
}

extern "C" void kernel_launch(void* const* d_in, const int* in_sizes, int n_in,
                              void* d_out, int out_size, void* d_ws, size_t ws_size,
                              hipStream_t stream) {
    const float* seq  = (const float*)d_in[0];
    const float* W    = (const float*)d_in[1];
    const float* b    = (const float*)d_in[2];
    const int*   erow = (const int*)d_in[3];
    const int*   ecol = (const int*)d_in[4];
    const float* eval = (const float*)d_in[5];
    float* out = (float*)d_out;

    float* wsf = (float*)d_ws;
    unsigned short* h = (unsigned short*)(wsf + OFF_H);
    uint2* ebin = (uint2*)(wsf + OFF_EBIN);
    int*   gcur = (int*)(wsf + OFF_CUR);

    hipMemsetAsync(gcur, 0, NBUCK * sizeof(int), stream);
    k1_scatter_gemm<<<NCHUNK + NGB, 256, 0, stream>>>(seq, W, h, erow, ecol,
                                                      eval, gcur, ebin);
    k2_fill_gather<<<NBUCK * 4, 512, 0, stream>>>(h, ebin, gcur, b, out);
}